// Round 1
// baseline (176.508 us; speedup 1.0000x reference)
//
#include <hip/hip_runtime.h>
#include <hip/hip_bf16.h>

// loss = mean_n( logsumexp([pos_n, (online@queue)_n]/t) - pos_n/t )   (fwd: alpha mix = identity)
// v10 = 2-stripe pipeline per block. BN=64 col-stripes; block = 2 adjacent stripes (128 cols).
//   stage(stripe0, 32KB LDS) -> [compute stripe0 || stage stripe1 via registers, interleaved
//   at group boundaries (issue-early / write-late)] -> compute stripe1.
//   Stripe-0 per-row (M,S) parked in 8KB LDS scratch, merged at stripe-1 epilogue so
//   partials stay [512][1024] and finalize_rows is unchanged. LDS 72KB -> 2 blocks/CU.

#define NROWS 1024
#define DDIM  256
#define KQ    65536
#define BN    64
#define NPART 512
#define LN2_F 0.69314718055994531f

typedef short  short8  __attribute__((ext_vector_type(8)));
typedef float  floatx4 __attribute__((ext_vector_type(4)));

__device__ __forceinline__ unsigned short f2bf(float f) {
    unsigned int u = __float_as_uint(f);
    u += 0x7FFFu + ((u >> 16) & 1u);   // RNE
    return (unsigned short)(u >> 16);
}

// DPP lane-permute (row-of-16 scope). quad_perm xor1=0xB1, xor2=0x4E,
// row_half_mirror=0x141 (pairs quads), row_mirror=0x140 (pairs octets).
#define DPPMOV(x, ctrl) \
    __uint_as_float(__builtin_amdgcn_mov_dpp(__float_as_uint(x), (ctrl), 0xF, 0xF, true))

__device__ __forceinline__ float dpp16_max(float x) {
    x = fmaxf(x, DPPMOV(x, 0xB1));
    x = fmaxf(x, DPPMOV(x, 0x4E));
    x = fmaxf(x, DPPMOV(x, 0x141));
    x = fmaxf(x, DPPMOV(x, 0x140));
    return x;   // all 16 lanes of the row-of-16 hold the max
}
__device__ __forceinline__ float dpp16_sum(float x) {
    x += DPPMOV(x, 0xB1);
    x += DPPMOV(x, 0x4E);
    x += DPPMOV(x, 0x141);
    x += DPPMOV(x, 0x140);
    return x;
}

// ---- A conversion: bf16(A/(t*ln2)); also zeroes the output accumulator ----
__global__ __launch_bounds__(256)
void conv_a(const float* __restrict__ A, const float* __restrict__ temp,
            unsigned short* __restrict__ Ab, float* __restrict__ out)
{
    if (blockIdx.x == 0 && threadIdx.x == 0) out[0] = 0.0f;
    const float s = 1.0f / (temp[0] * LN2_F);
    const int i = blockIdx.x * 256 + threadIdx.x;       // 65536 threads, one float4 each
    const floatx4 v = ((const floatx4*)A)[i];
    ushort4 w;
    w.x = f2bf(v.x * s); w.y = f2bf(v.y * s);
    w.z = f2bf(v.z * s); w.w = f2bf(v.w * s);
    ((ushort4*)Ab)[i] = w;
}

// ---- fused GEMM + online-softmax partials. 512 blocks x 256 thr; block = two 64-col stripes ----
__global__ __launch_bounds__(256, 2)
void gemm_softmax(const unsigned short* __restrict__ Ab,   // [1024][256] bf16, pre-scaled
                  const float* __restrict__ Q,             // [256][65536] fp32
                  float2* __restrict__ partials)           // [NPART][1024]  (part-major)
{
    __shared__ __align__(16) unsigned short Bl[2][BN * DDIM];  // 2 x 32 KB, swizzled
    __shared__ __align__(16) float2 smP[NROWS];                // 8 KB stripe-0 (M,S) scratch

    const int tid  = threadIdx.x;
    const int lane = tid & 63;
    const int wave = tid >> 6;          // 0..3 (row bands within a group-pass)
    const int l15  = lane & 15;
    const int quad = lane >> 4;
    const int nb   = blockIdx.x;        // 0..511
    const int cb0  = nb * (2 * BN);     // col base of stripe 0

    // 512 tasks per stripe: ko-octet (k rows) x ny-quad (cols); 2 tasks/thread (h=0,1)
    auto stage_issue = [&](int h, int cb, floatx4* v) {
        const int t2 = h * 256 + tid;
        const int ny = t2 & 15;
        const int ko = t2 >> 4;             // 0..31
        #pragma unroll
        for (int j = 0; j < 8; ++j)
            v[j] = __builtin_nontemporal_load(
                       (const floatx4*)(Q + (size_t)(ko * 8 + j) * KQ + cb + ny * 4));
    };
    auto stage_write = [&](int h, unsigned short* bl, const floatx4* v) {
        const int t2 = h * 256 + tid;
        const int ny = t2 & 15;
        const int ko = t2 >> 4;
        #pragma unroll
        for (int i2 = 0; i2 < 4; ++i2) {
            const int n = ny * 4 + i2;
            const int phys = ko ^ (n & 15);      // 16B-chunk XOR swizzle
            short8 w;
            #pragma unroll
            for (int j = 0; j < 8; ++j) w[j] = (short)f2bf(v[j][i2]);
            *(short8*)&bl[n * DDIM + phys * 8] = w;
        }
    };

    // one 64-row x 64-col group: full-K MFMA + online-softmax epilogue.
    // merge=false: park (M,S) in smP.  merge=true: merge with smP, store to partials[nb].
    auto compute_group = [&](const unsigned short* bl, int rowbase, bool merge) {
        const unsigned short* apb = Ab + (size_t)(rowbase + l15) * DDIM + quad * 8;
        const char* blc = (const char*)bl;
        floatx4 acc[4][4] = {};
        short8 afA[4], afB[4], bfA[4], bfB[4];

        // prologue: s=0 fragments
        #pragma unroll
        for (int i = 0; i < 4; ++i)
            afA[i] = *(const short8*)(apb + i * 16 * DDIM);
        {
            const int vb = l15 * 512 + ((quad ^ l15) * 16);
            #pragma unroll
            for (int j = 0; j < 4; ++j)
                bfA[j] = *(const short8*)(blc + vb + j * 8192);
        }
        #pragma unroll 1
        for (int sp = 0; sp < 4; ++sp) {
            const int s1 = 2 * sp + 1;
            // prefetch odd step
            #pragma unroll
            for (int i = 0; i < 4; ++i)
                afB[i] = *(const short8*)(apb + i * 16 * DDIM + s1 * 32);
            {
                const int vb = l15 * 512 + (((4 * s1 + quad) ^ l15) * 16);
                #pragma unroll
                for (int j = 0; j < 4; ++j)
                    bfB[j] = *(const short8*)(blc + vb + j * 8192);
            }
            // compute even step
            #pragma unroll
            for (int i = 0; i < 4; ++i)
                #pragma unroll
                for (int j = 0; j < 4; ++j)
                    acc[i][j] = __builtin_amdgcn_mfma_f32_16x16x32_bf16(afA[i], bfA[j], acc[i][j], 0, 0, 0);

            const int s2 = (2 * sp + 2) & 7;   // 2,4,6,0 (sp==3 loads are dead; cheap)
            #pragma unroll
            for (int i = 0; i < 4; ++i)
                afA[i] = *(const short8*)(apb + i * 16 * DDIM + s2 * 32);
            {
                const int vb = l15 * 512 + (((4 * s2 + quad) ^ l15) * 16);
                #pragma unroll
                for (int j = 0; j < 4; ++j)
                    bfA[j] = *(const short8*)(blc + vb + j * 8192);
            }
            // compute odd step
            #pragma unroll
            for (int i = 0; i < 4; ++i)
                #pragma unroll
                for (int j = 0; j < 4; ++j)
                    acc[i][j] = __builtin_amdgcn_mfma_f32_16x16x32_bf16(afB[i], bfB[j], acc[i][j], 0, 0, 0);
        }

        // epilogue: base-2 logits. C layout: col(n)=lane&15, row(m)=quad*4+reg (verified).
        #pragma unroll
        for (int i = 0; i < 4; ++i) {
            float2 tmp[4];
            #pragma unroll
            for (int r = 0; r < 4; ++r) {
                float mx = acc[i][0][r];
                #pragma unroll
                for (int j = 1; j < 4; ++j) mx = fmaxf(mx, acc[i][j][r]);
                mx = dpp16_max(mx);
                float s2s = 0.f;
                #pragma unroll
                for (int j = 0; j < 4; ++j)
                    s2s += __builtin_amdgcn_exp2f(acc[i][j][r] - mx);
                s2s = dpp16_sum(s2s);
                tmp[r] = make_float2(mx, s2s);
            }
            if (l15 == 0) {
                const int row = rowbase + i * 16 + quad * 4;   // 4 quad-leaders: 128 B contiguous
                if (!merge) {
                    floatx4* dst = (floatx4*)&smP[row];
                    floatx4 w0 = {tmp[0].x, tmp[0].y, tmp[1].x, tmp[1].y};
                    floatx4 w1 = {tmp[2].x, tmp[2].y, tmp[3].x, tmp[3].y};
                    dst[0] = w0; dst[1] = w1;
                } else {
                    const floatx4 p0 = ((const floatx4*)&smP[row])[0];
                    const floatx4 p1 = ((const floatx4*)&smP[row])[1];
                    const float m0[4] = {p0.x, p0.z, p1.x, p1.z};
                    const float s0[4] = {p0.y, p0.w, p1.y, p1.w};
                    float2 o[4];
                    #pragma unroll
                    for (int r = 0; r < 4; ++r) {
                        const float M2 = fmaxf(m0[r], tmp[r].x);
                        const float S  = s0[r] * __builtin_amdgcn_exp2f(m0[r] - M2)
                                       + tmp[r].y * __builtin_amdgcn_exp2f(tmp[r].x - M2);
                        o[r] = make_float2(M2, S);
                    }
                    floatx4* dst = (floatx4*)(partials + (size_t)nb * NROWS + row);
                    floatx4 w0 = {o[0].x, o[0].y, o[1].x, o[1].y};
                    floatx4 w1 = {o[2].x, o[2].y, o[3].x, o[3].y};
                    __builtin_nontemporal_store(w0, dst);
                    __builtin_nontemporal_store(w1, dst + 1);
                }
            }
        }
    };

    // ---- stage stripe 0 (fully exposed; only 32 MB chip-wide) ----
    {
        floatx4 v0[8], v1[8];
        stage_issue(0, cb0, v0);
        stage_issue(1, cb0, v1);
        stage_write(0, &Bl[0][0], v0);
        stage_write(1, &Bl[0][0], v1);
    }
    __syncthreads();

    // ---- stripe 0 compute with stripe-1 staging interleaved (issue-early / write-late) ----
    floatx4 sv[8];
    stage_issue(0, cb0 + BN, sv);                       // half 0 in flight over group 0
    compute_group(&Bl[0][0], 0 * 256 + wave * 64, false);
    stage_write(0, &Bl[1][0], sv);
    stage_issue(1, cb0 + BN, sv);                       // half 1 in flight over group 1
    compute_group(&Bl[0][0], 1 * 256 + wave * 64, false);
    stage_write(1, &Bl[1][0], sv);
    compute_group(&Bl[0][0], 2 * 256 + wave * 64, false);
    compute_group(&Bl[0][0], 3 * 256 + wave * 64, false);
    __syncthreads();                                    // buf1 fully staged

    // ---- stripe 1 compute; merge with stripe-0 (M,S) and store partials ----
    compute_group(&Bl[1][0], 0 * 256 + wave * 64, true);
    compute_group(&Bl[1][0], 1 * 256 + wave * 64, true);
    compute_group(&Bl[1][0], 2 * 256 + wave * 64, true);
    compute_group(&Bl[1][0], 3 * 256 + wave * 64, true);
}

// ---- combine partials per row + positive logit (computed inline) + atomic mean ----
// Grid: 64 blocks x 256 threads. Block owns 16 rows; 16 part-groups of 32 parts.
__global__ __launch_bounds__(256)
void finalize_rows(const float2* __restrict__ partials,   // [NPART][1024]
                   const float* __restrict__ online,
                   const float* __restrict__ mom,
                   const float* __restrict__ temp,
                   float* __restrict__ out)
{
    const int t = threadIdx.x;
    __shared__ float2 sm[16][17];
    __shared__ float sm_pos[16];

    // phase 1: positive-pair logit, 16 threads per row (rows r2 = t>>4)
    {
        const float s = 1.0f / (temp[0] * LN2_F);
        const int r2 = t >> 4, c2 = t & 15;
        const float* po = online + (size_t)(blockIdx.x * 16 + r2) * DDIM + c2 * 16;
        const float* pm = mom    + (size_t)(blockIdx.x * 16 + r2) * DDIM + c2 * 16;
        float d = 0.f;
        #pragma unroll
        for (int w = 0; w < 4; ++w) {
            const floatx4 a = *(const floatx4*)(po + w * 4);
            const floatx4 b = *(const floatx4*)(pm + w * 4);
            d += a.x * b.x + a.y * b.y + a.z * b.z + a.w * b.w;
        }
        d = dpp16_sum(d);
        if (c2 == 0) sm_pos[r2] = d * s;    // base-2-domain positive logit
    }

    // phase 2: combine negative partials; rl = row-in-block, grp = part group
    const int rl  = t & 15;
    const int grp = t >> 4;
    const int row = blockIdx.x * 16 + rl;

    float M = -3.0e38f, S = 0.f;
    #pragma unroll 1
    for (int pb = 0; pb < 32; pb += 8) {
        float2 v[8];
        #pragma unroll
        for (int j = 0; j < 8; ++j)
            v[j] = partials[(size_t)(grp * 32 + pb + j) * NROWS + row];
        #pragma unroll
        for (int j = 0; j < 8; ++j) {
            const float M2 = fmaxf(M, v[j].x);
            S = S * __builtin_amdgcn_exp2f(M - M2) + v[j].y * __builtin_amdgcn_exp2f(v[j].x - M2);
            M = M2;
        }
    }
    sm[grp][rl] = make_float2(M, S);
    __syncthreads();

    if (t < 64) {
        float val = 0.f;
        if (t < 16) {
            float Mm = -3.0e38f, Ss = 0.f;
            #pragma unroll
            for (int g2 = 0; g2 < 16; ++g2) {
                const float2 v = sm[g2][t];
                const float M2 = fmaxf(Mm, v.x);
                Ss = Ss * __builtin_amdgcn_exp2f(Mm - M2) + v.y * __builtin_amdgcn_exp2f(v.x - M2);
                Mm = M2;
            }
            const float p  = sm_pos[t];
            const float M2 = fmaxf(Mm, p);
            const float L  = Ss * __builtin_amdgcn_exp2f(Mm - M2) + __builtin_amdgcn_exp2f(p - M2);
            val = (M2 + __builtin_amdgcn_logf(L) - p) * LN2_F;   // back to natural log
        }
        val += __shfl_xor(val, 1, 64);
        val += __shfl_xor(val, 2, 64);
        val += __shfl_xor(val, 4, 64);
        val += __shfl_xor(val, 8, 64);
        val += __shfl_xor(val, 16, 64);
        val += __shfl_xor(val, 32, 64);
        if (t == 0) atomicAdd(out, val * (1.0f / (float)NROWS));
    }
}

extern "C" void kernel_launch(void* const* d_in, const int* in_sizes, int n_in,
                              void* d_out, int out_size, void* d_ws, size_t ws_size,
                              hipStream_t stream)
{
    const float* online = (const float*)d_in[0];   // [1024][256]
    const float* mom    = (const float*)d_in[1];   // [1024][256]
    const float* queue  = (const float*)d_in[2];   // [256][65536]
    const float* temp   = (const float*)d_in[3];   // [1]
    float* out = (float*)d_out;

    // ws: Ab bf16 [1024][256] (512 KB) | partials float2 [512][1024] (4 MB)
    char* ws = (char*)d_ws;
    unsigned short* Ab = (unsigned short*)ws;
    float2* partials   = (float2*)(ws + 524288);

    conv_a<<<256, 256, 0, stream>>>(online, temp, Ab, out);
    gemm_softmax<<<KQ / (2 * BN), 256, 0, stream>>>(Ab, queue, partials);
    finalize_rows<<<64, 256, 0, stream>>>(partials, online, mom, temp, out);
}

// Round 2
// 146.041 us; speedup vs baseline: 1.2086x; 1.2086x over previous
//
#include <hip/hip_runtime.h>
#include <hip/hip_bf16.h>

// loss = mean_n( logsumexp([pos_n, (online@queue)_n]/t) - pos_n/t )   (fwd: alpha mix = identity)
// v11 = v9 geometry (BN=128 stripe, single barrier, same swizzle/epilogue/partials) but
//       512-thread blocks with wave-tile 32x128 (acc[2][8] = 64 AGPR) and NO register
//       ping-pong, targeting <=128 unified regs/wave -> 4 waves/SIMD (16 waves/CU).
//       Occupancy-driven latency hiding (v10 post-mortem: both pipes <35% busy at 2/SIMD).

#define NROWS 1024
#define DDIM  256
#define KQ    65536
#define BN    128
#define NPART 512
#define LN2_F 0.69314718055994531f

typedef short  short8  __attribute__((ext_vector_type(8)));
typedef float  floatx4 __attribute__((ext_vector_type(4)));

__device__ __forceinline__ unsigned short f2bf(float f) {
    unsigned int u = __float_as_uint(f);
    u += 0x7FFFu + ((u >> 16) & 1u);   // RNE
    return (unsigned short)(u >> 16);
}

// DPP lane-permute (row-of-16 scope). quad_perm xor1=0xB1, xor2=0x4E,
// row_half_mirror=0x141 (pairs quads), row_mirror=0x140 (pairs octets).
#define DPPMOV(x, ctrl) \
    __uint_as_float(__builtin_amdgcn_mov_dpp(__float_as_uint(x), (ctrl), 0xF, 0xF, true))

__device__ __forceinline__ float dpp16_max(float x) {
    x = fmaxf(x, DPPMOV(x, 0xB1));
    x = fmaxf(x, DPPMOV(x, 0x4E));
    x = fmaxf(x, DPPMOV(x, 0x141));
    x = fmaxf(x, DPPMOV(x, 0x140));
    return x;   // all 16 lanes of the row-of-16 hold the max
}
__device__ __forceinline__ float dpp16_sum(float x) {
    x += DPPMOV(x, 0xB1);
    x += DPPMOV(x, 0x4E);
    x += DPPMOV(x, 0x141);
    x += DPPMOV(x, 0x140);
    return x;
}

// ---- A conversion: bf16(A/(t*ln2)); also zeroes the output accumulator ----
__global__ __launch_bounds__(256)
void conv_a(const float* __restrict__ A, const float* __restrict__ temp,
            unsigned short* __restrict__ Ab, float* __restrict__ out)
{
    if (blockIdx.x == 0 && threadIdx.x == 0) out[0] = 0.0f;
    const float s = 1.0f / (temp[0] * LN2_F);
    const int i = blockIdx.x * 256 + threadIdx.x;       // 65536 threads, one float4 each
    const floatx4 v = ((const floatx4*)A)[i];
    ushort4 w;
    w.x = f2bf(v.x * s); w.y = f2bf(v.y * s);
    w.z = f2bf(v.z * s); w.w = f2bf(v.w * s);
    ((ushort4*)Ab)[i] = w;
}

// ---- fused GEMM + online-softmax partials. 512 blocks x 512 thr; block = one 128-col stripe ----
__global__ __launch_bounds__(512, 4)
void gemm_softmax(const unsigned short* __restrict__ Ab,   // [1024][256] bf16, pre-scaled
                  const float* __restrict__ Q,             // [256][65536] fp32
                  float2* __restrict__ partials)           // [NPART][1024]  (part-major)
{
    __shared__ __align__(16) unsigned short Bl[BN * DDIM];   // [n][k] bf16, 64 KB, swizzled

    const int tid  = threadIdx.x;
    const int lane = tid & 63;
    const int wave = tid >> 6;          // 0..7 (32-row bands within a group-pass)
    const int l15  = lane & 15;
    const int quad = lane >> 4;
    const int nb   = blockIdx.x;        // 0..511
    const int nbase = nb * BN;

    // ---- stage B once: Q[k][nbase..+127] fp32 -> Bl[n][k] bf16 (register transpose) ----
    // 1024 tasks (ko-octet x ny-quad), 2 per thread, one at a time (32 VGPR peak).
    #pragma unroll 1
    for (int iter = 0; iter < 2; ++iter) {
        const int t2 = iter * 512 + tid;
        const int ny = t2 & 31;             // n-quad (4 cols)
        const int ko = t2 >> 5;             // k-octet (8 rows), 0..31
        floatx4 v[8];
        #pragma unroll
        for (int j = 0; j < 8; ++j)
            v[j] = __builtin_nontemporal_load(
                       (const floatx4*)(Q + (size_t)(ko * 8 + j) * KQ + nbase + ny * 4));
        #pragma unroll
        for (int i2 = 0; i2 < 4; ++i2) {
            const int n = ny * 4 + i2;
            const int phys = ko ^ (n & 15);      // 16B-chunk XOR swizzle
            short8 w;
            #pragma unroll
            for (int j = 0; j < 8; ++j)
                w[j] = (short)f2bf(v[j][i2]);
            *(short8*)&Bl[n * DDIM + phys * 8] = w;
        }
    }
    __syncthreads();   // the ONLY barrier

    #pragma unroll 1
    for (int g = 0; g < 4; ++g) {
        const int rowbase = g * 256 + wave * 32;
        const unsigned short* apb = Ab + (size_t)(rowbase + l15) * DDIM + quad * 8;

        floatx4 acc[2][8] = {};
        short8 af[2], bf[8];

        #pragma unroll 1
        for (int s = 0; s < 8; ++s) {
            #pragma unroll
            for (int i = 0; i < 2; ++i)
                af[i] = *(const short8*)(apb + i * 16 * DDIM + s * 32);
            {
                const int vb = l15 * 512 + (((4 * s + quad) ^ l15) * 16);
                #pragma unroll
                for (int j = 0; j < 8; ++j)
                    bf[j] = *(const short8*)((const char*)Bl + vb + j * 8192);
            }
            #pragma unroll
            for (int i = 0; i < 2; ++i)
                #pragma unroll
                for (int j = 0; j < 8; ++j)
                    acc[i][j] = __builtin_amdgcn_mfma_f32_16x16x32_bf16(af[i], bf[j], acc[i][j], 0, 0, 0);
        }

        // epilogue: base-2 logits. C layout: col(n)=lane&15, row(m)=quad*4+reg (verified).
        #pragma unroll
        for (int i = 0; i < 2; ++i) {
            float2 tmp[4];
            #pragma unroll
            for (int r = 0; r < 4; ++r) {
                float mx = acc[i][0][r];
                #pragma unroll
                for (int j = 1; j < 8; ++j) mx = fmaxf(mx, acc[i][j][r]);
                mx = dpp16_max(mx);
                float s2 = 0.f;
                #pragma unroll
                for (int j = 0; j < 8; ++j)
                    s2 += __builtin_amdgcn_exp2f(acc[i][j][r] - mx);
                s2 = dpp16_sum(s2);
                tmp[r] = make_float2(mx, s2);
            }
            if (l15 == 0) {
                // 4 quad-leader lanes cover 128 contiguous bytes
                const int row = rowbase + i * 16 + quad * 4;
                floatx4* dst = (floatx4*)(partials + (size_t)nb * NROWS + row);
                floatx4 w0 = {tmp[0].x, tmp[0].y, tmp[1].x, tmp[1].y};
                floatx4 w1 = {tmp[2].x, tmp[2].y, tmp[3].x, tmp[3].y};
                __builtin_nontemporal_store(w0, dst);
                __builtin_nontemporal_store(w1, dst + 1);
            }
        }
    }
}

// ---- combine partials per row + positive logit (computed inline) + atomic mean ----
// Grid: 64 blocks x 256 threads. Block owns 16 rows; 16 part-groups of 32 parts.
__global__ __launch_bounds__(256)
void finalize_rows(const float2* __restrict__ partials,   // [NPART][1024]
                   const float* __restrict__ online,
                   const float* __restrict__ mom,
                   const float* __restrict__ temp,
                   float* __restrict__ out)
{
    const int t = threadIdx.x;
    __shared__ float2 sm[16][17];
    __shared__ float sm_pos[16];

    // phase 1: positive-pair logit, 16 threads per row (rows r2 = t>>4)
    {
        const float s = 1.0f / (temp[0] * LN2_F);
        const int r2 = t >> 4, c2 = t & 15;
        const float* po = online + (size_t)(blockIdx.x * 16 + r2) * DDIM + c2 * 16;
        const float* pm = mom    + (size_t)(blockIdx.x * 16 + r2) * DDIM + c2 * 16;
        float d = 0.f;
        #pragma unroll
        for (int w = 0; w < 4; ++w) {
            const floatx4 a = *(const floatx4*)(po + w * 4);
            const floatx4 b = *(const floatx4*)(pm + w * 4);
            d += a.x * b.x + a.y * b.y + a.z * b.z + a.w * b.w;
        }
        d = dpp16_sum(d);
        if (c2 == 0) sm_pos[r2] = d * s;    // base-2-domain positive logit
    }

    // phase 2: combine negative partials; rl = row-in-block, grp = part group
    const int rl  = t & 15;
    const int grp = t >> 4;
    const int row = blockIdx.x * 16 + rl;

    float M = -3.0e38f, S = 0.f;
    #pragma unroll 1
    for (int pb = 0; pb < 32; pb += 8) {
        float2 v[8];
        #pragma unroll
        for (int j = 0; j < 8; ++j)
            v[j] = partials[(size_t)(grp * 32 + pb + j) * NROWS + row];
        #pragma unroll
        for (int j = 0; j < 8; ++j) {
            const float M2 = fmaxf(M, v[j].x);
            S = S * __builtin_amdgcn_exp2f(M - M2) + v[j].y * __builtin_amdgcn_exp2f(v[j].x - M2);
            M = M2;
        }
    }
    sm[grp][rl] = make_float2(M, S);
    __syncthreads();

    if (t < 64) {
        float val = 0.f;
        if (t < 16) {
            float Mm = -3.0e38f, Ss = 0.f;
            #pragma unroll
            for (int g2 = 0; g2 < 16; ++g2) {
                const float2 v = sm[g2][t];
                const float M2 = fmaxf(Mm, v.x);
                Ss = Ss * __builtin_amdgcn_exp2f(Mm - M2) + v.y * __builtin_amdgcn_exp2f(v.x - M2);
                Mm = M2;
            }
            const float p  = sm_pos[t];
            const float M2 = fmaxf(Mm, p);
            const float L  = Ss * __builtin_amdgcn_exp2f(Mm - M2) + __builtin_amdgcn_exp2f(p - M2);
            val = (M2 + __builtin_amdgcn_logf(L) - p) * LN2_F;   // back to natural log
        }
        val += __shfl_xor(val, 1, 64);
        val += __shfl_xor(val, 2, 64);
        val += __shfl_xor(val, 4, 64);
        val += __shfl_xor(val, 8, 64);
        val += __shfl_xor(val, 16, 64);
        val += __shfl_xor(val, 32, 64);
        if (t == 0) atomicAdd(out, val * (1.0f / (float)NROWS));
    }
}

extern "C" void kernel_launch(void* const* d_in, const int* in_sizes, int n_in,
                              void* d_out, int out_size, void* d_ws, size_t ws_size,
                              hipStream_t stream)
{
    const float* online = (const float*)d_in[0];   // [1024][256]
    const float* mom    = (const float*)d_in[1];   // [1024][256]
    const float* queue  = (const float*)d_in[2];   // [256][65536]
    const float* temp   = (const float*)d_in[3];   // [1]
    float* out = (float*)d_out;

    // ws: Ab bf16 [1024][256] (512 KB) | partials float2 [512][1024] (4 MB)
    char* ws = (char*)d_ws;
    unsigned short* Ab = (unsigned short*)ws;
    float2* partials   = (float2*)(ws + 524288);

    conv_a<<<256, 256, 0, stream>>>(online, temp, Ab, out);
    gemm_softmax<<<KQ / BN, 512, 0, stream>>>(Ab, queue, partials);
    finalize_rows<<<64, 256, 0, stream>>>(partials, online, mom, temp, out);
}